// Round 1
// 188.219 us; speedup vs baseline: 1.0610x; 1.0610x over previous
//
#include <hip/hip_runtime.h>
#include <hip/hip_bf16.h>
#include <stdint.h>

#define N_BATCH 4096
#define D_DIM   1024
#define M_ROWS  8192                     // 2N
#define TINV    2.0f                     // 1/temperature
#define EXP_SCALE 2.8853900817779268f    // log2(e)/t  (t=0.5)
#define LN2 0.6931471805599453f
#define NB 64                            // 8192/128 tiles per dim
#define NTRI 2080                        // NB*(NB+1)/2 upper-tri tiles

typedef __bf16 bf16x8 __attribute__((ext_vector_type(8)));
typedef float  f32x4  __attribute__((ext_vector_type(4)));

__device__ __forceinline__ void load_lds16(const __bf16* g, __bf16* l) {
    __builtin_amdgcn_global_load_lds(
        (const __attribute__((address_space(1))) void*)g,
        (__attribute__((address_space(3))) void*)l, 16, 0, 0);
}

// ---- kernel 1: fused L2-normalize (bf16 Z out) + exact fp32 positives ----
__global__ __launch_bounds__(256) void norm_pos_kernel(
    const float* __restrict__ emb_i, const float* __restrict__ emb_j,
    __bf16* __restrict__ zb, float* __restrict__ pos, float* __restrict__ denom)
{
    int i = blockIdx.x;
    int t = threadIdx.x;
    float4 va = ((const float4*)(emb_i + (size_t)i * D_DIM))[t];
    float4 vb = ((const float4*)(emb_j + (size_t)i * D_DIM))[t];
    float ssa = va.x*va.x + va.y*va.y + va.z*va.z + va.w*va.w;
    float ssb = vb.x*vb.x + vb.y*vb.y + vb.z*vb.z + vb.w*vb.w;
    float dot = va.x*vb.x + va.y*vb.y + va.z*vb.z + va.w*vb.w;
    #pragma unroll
    for (int m = 1; m < 64; m <<= 1) {
        ssa += __shfl_xor(ssa, m, 64);
        ssb += __shfl_xor(ssb, m, 64);
        dot += __shfl_xor(dot, m, 64);
    }
    __shared__ float ra[4], rb[4], rd[4];
    int wv = t >> 6;
    if ((t & 63) == 0) { ra[wv] = ssa; rb[wv] = ssb; rd[wv] = dot; }
    __syncthreads();
    float SSA = ra[0] + ra[1] + ra[2] + ra[3];
    float SSB = rb[0] + rb[1] + rb[2] + rb[3];
    float na = fmaxf(sqrtf(SSA), 1e-12f);
    float nb = fmaxf(sqrtf(SSB), 1e-12f);
    float sa = 1.0f / na, sb = 1.0f / nb;
    union { __bf16 h[4]; uint2 u; } cv;
    cv.h[0] = (__bf16)(va.x * sa); cv.h[1] = (__bf16)(va.y * sa);
    cv.h[2] = (__bf16)(va.z * sa); cv.h[3] = (__bf16)(va.w * sa);
    *(uint2*)(zb + (size_t)i * D_DIM + t * 4) = cv.u;
    cv.h[0] = (__bf16)(vb.x * sb); cv.h[1] = (__bf16)(vb.y * sb);
    cv.h[2] = (__bf16)(vb.z * sb); cv.h[3] = (__bf16)(vb.w * sb);
    *(uint2*)(zb + (size_t)(i + N_BATCH) * D_DIM + t * 4) = cv.u;
    if (t == 0) {
        float DOT = rd[0] + rd[1] + rd[2] + rd[3];
        pos[i] = DOT / (na * nb);
        denom[i] = 0.0f;
        denom[i + N_BATCH] = 0.0f;
    }
}

// ---- kernel 2: fused sim = Z Z^T -> exp -> masked row/col sums -----------
// Changes vs prev round:
//  (a) 1-D TRIANGULAR grid (2080 blocks) -- no dead bx<by blocks.
//  (b) LDS bank-conflict swizzle: [128][32]-bf16 rows are 64 B, so quad q's
//      16 lanes hit only 2 of 8 bank granules (8-way conflict, 4 extra
//      cyc/ds_read measured). Fix: 16B-slot ^= (row>>1)&3, applied BOTH
//      sides -- pre-swizzled global source octet (global_load_lds writes
//      linearly) + swizzled ds_read column.  8 consecutive lanes now cover
//      all 8 granules -> residual 2-way = free.
__global__ __launch_bounds__(256, 3) void simexp_kernel(
    const __bf16* __restrict__ Z, float* __restrict__ denom)
{
    // decode linear idx -> (by, bx) with bx >= by
    int idx = blockIdx.x;
    int by = (int)((129.0f - sqrtf(16641.0f - 8.0f * (float)idx)) * 0.5f);
    if (by > NB - 1) by = NB - 1;
    int off = (by * (129 - by)) >> 1;           // tiles before row `by`
    while (off > idx)                 { --by; off = (by * (129 - by)) >> 1; }
    while (off + (NB - by) <= idx)    { off += NB - by; ++by; }
    int bx = by + (idx - off);

    int tile_m = by * 128, tile_n = bx * 128;

    // [buf][A=0/B=1][128*32 bf16]  -> 32 KB total
    __shared__ __align__(16) __bf16 sh[2][2][128 * 32];

    int t    = threadIdx.x;
    int wv   = t >> 6;
    int lane = t & 63;
    int wave_m = (wv >> 1) * 64;
    int wave_n = (wv & 1) * 64;
    int quad = lane >> 4;
    int l15  = lane & 15;

    // staging: thread t fills LDS slot (row=t>>2, slot=t&3); that slot must
    // hold global octet  o = slot ^ ((row>>1)&3)  = (t&3) ^ ((t>>3)&3)
    int srow = t >> 2;
    int soct = ((t & 3) ^ ((t >> 3) & 3)) * 8;
    const __bf16* gA = Z + (size_t)(tile_m + srow) * D_DIM + soct;
    const __bf16* gB = Z + (size_t)(tile_n + srow) * D_DIM + soct;

    // read column for octet `quad` of row (16a + l15): quad ^ ((l15>>1)&3)
    int swz = (quad ^ ((l15 >> 1) & 3)) * 8;

    f32x4 acc[4][4] = {};

    // prologue: stage k=0 into buf 0, drain once
    load_lds16(gA,                  &sh[0][0][wv * 512]);
    load_lds16(gA + 64 * D_DIM,     &sh[0][0][2048 + wv * 512]);
    load_lds16(gB,                  &sh[0][1][wv * 512]);
    load_lds16(gB + 64 * D_DIM,     &sh[0][1][2048 + wv * 512]);
    __syncthreads();

    for (int it = 0; it < 32; ++it) {
        int p = it & 1;
        if (it + 1 < 32) {
            int k0 = (it + 1) * 32;
            load_lds16(gA + k0,              &sh[p ^ 1][0][wv * 512]);
            load_lds16(gA + 64 * D_DIM + k0, &sh[p ^ 1][0][2048 + wv * 512]);
            load_lds16(gB + k0,              &sh[p ^ 1][1][wv * 512]);
            load_lds16(gB + 64 * D_DIM + k0, &sh[p ^ 1][1][2048 + wv * 512]);
        }
        bf16x8 af[4], bf[4];
        #pragma unroll
        for (int f = 0; f < 4; ++f) {
            af[f] = *(const bf16x8*)&sh[p][0][(wave_m + f * 16 + l15) * 32 + swz];
            bf[f] = *(const bf16x8*)&sh[p][1][(wave_n + f * 16 + l15) * 32 + swz];
        }
        #pragma unroll
        for (int fm = 0; fm < 4; ++fm)
            #pragma unroll
            for (int fn = 0; fn < 4; ++fn)
                acc[fm][fn] = __builtin_amdgcn_mfma_f32_16x16x32_bf16(
                    af[fm], bf[fn], acc[fm][fn], 0, 0, 0);
        __syncthreads();   // consumers done with sh[p]; drains DMA(it+1)
    }

    // epilogue: e = exp2(sim*log2(e)/t) only where c>r; row + col reductions
    int rbase = tile_m + wave_m + quad * 4;
    int cbase = tile_n + wave_n + l15;
    float colacc[4] = {0.f, 0.f, 0.f, 0.f};
    #pragma unroll
    for (int fm = 0; fm < 4; ++fm) {
        #pragma unroll
        for (int r = 0; r < 4; ++r) {
            int rg = rbase + fm * 16 + r;
            float rowacc = 0.f;
            #pragma unroll
            for (int fn = 0; fn < 4; ++fn) {
                int cg = cbase + fn * 16;
                float e = (cg > rg)
                    ? __builtin_amdgcn_exp2f(acc[fm][fn][r] * EXP_SCALE)
                    : 0.f;
                rowacc += e;
                colacc[fn] += e;
            }
            rowacc += __shfl_xor(rowacc, 1, 64);
            rowacc += __shfl_xor(rowacc, 2, 64);
            rowacc += __shfl_xor(rowacc, 4, 64);
            rowacc += __shfl_xor(rowacc, 8, 64);
            if (l15 == 0) atomicAdd(&denom[rg], rowacc);
        }
    }
    #pragma unroll
    for (int fn = 0; fn < 4; ++fn) {
        float s = colacc[fn];
        s += __shfl_xor(s, 16, 64);
        s += __shfl_xor(s, 32, 64);
        if (quad == 0) atomicAdd(&denom[cbase + fn * 16], s);
    }
}

// ---- kernel 3: loss = [sum log(denom) - (2/t) sum pos] / 2N --------------
__global__ __launch_bounds__(256) void finalize_kernel(
    const float* __restrict__ denom, const float* __restrict__ pos,
    float* __restrict__ out)
{
    float a1 = 0.f, a2 = 0.f;
    for (int r = threadIdx.x; r < M_ROWS; r += 256)
        a1 += __builtin_amdgcn_logf(denom[r]) * LN2;   // v_log_f32 is log2
    for (int i = threadIdx.x; i < N_BATCH; i += 256)
        a2 += pos[i];
    #pragma unroll
    for (int m = 1; m < 64; m <<= 1) {
        a1 += __shfl_xor(a1, m, 64);
        a2 += __shfl_xor(a2, m, 64);
    }
    __shared__ float r1[4], r2[4];
    int wv = threadIdx.x >> 6;
    if ((threadIdx.x & 63) == 0) { r1[wv] = a1; r2[wv] = a2; }
    __syncthreads();
    if (threadIdx.x == 0) {
        float s1 = r1[0] + r1[1] + r1[2] + r1[3];
        float s2 = r2[0] + r2[1] + r2[2] + r2[3];
        out[0] = (s1 - 2.0f * TINV * s2) / (float)M_ROWS;
    }
}

extern "C" void kernel_launch(void* const* d_in, const int* in_sizes, int n_in,
                              void* d_out, int out_size, void* d_ws, size_t ws_size,
                              hipStream_t stream)
{
    const float* emb_i = (const float*)d_in[0];
    const float* emb_j = (const float*)d_in[1];
    float* out = (float*)d_out;

    char*   ws    = (char*)d_ws;
    __bf16* zb    = (__bf16*)ws;                                   // 16 MB
    float*  denom = (float*)(ws + (size_t)M_ROWS * D_DIM * 2);     // 32 KB
    float*  pos   = denom + M_ROWS;                                // 16 KB

    hipLaunchKernelGGL(norm_pos_kernel, dim3(N_BATCH), dim3(256), 0, stream,
                       emb_i, emb_j, zb, pos, denom);
    hipLaunchKernelGGL(simexp_kernel, dim3(NTRI), dim3(256), 0, stream,
                       zb, denom);
    hipLaunchKernelGGL(finalize_kernel, dim3(1), dim3(256), 0, stream,
                       denom, pos, out);
}